// Round 27
// baseline (282.608 us; speedup 1.0000x reference)
//
#include <hip/hip_runtime.h>
#include <math.h>

#define BATCH 131072
#define NTOT 320

typedef __attribute__((ext_vector_type(8))) short short8;
typedef __attribute__((ext_vector_type(4))) float f32x4;

// ---- ws layout (float offsets) ----
#define WS_D22   0          // 32*64
#define WS_VR    2048       // 320*64
#define WS_T     22528      // 320*64
#define WS_H     43008      // 320*320
#define WS_E     145408     // 128*128
#define WS_EINV  161792     // 128*128
#define WS_WEXT  178176     // 128*256
#define WS_D11   210944     // 64*64
#define WS_ILAM  215040     // 64
#define WS_BFU   215104     // ushort region below
#define U_WATH 0
#define U_WATL 16384
#define U_WOT  32768
#define U_WSPH 40960
#define U_WSPL 73728
#define U_D11T 106496       // 64*64 bf16, transposed D11 with iL on diagonal
// transient scratch inside WS_H:
#define WS_RC   (WS_H + 2048)   // 64*64  Rinv

__device__ inline unsigned short f2bf(float x){
    unsigned u = __builtin_bit_cast(unsigned, x);
    u += 0x7FFFu + ((u >> 16) & 1u);
    return (unsigned short)(u >> 16);
}
__device__ inline float bf2f(unsigned short h){
    unsigned u = ((unsigned)h) << 16;
    return __builtin_bit_cast(float, u);
}
__device__ inline unsigned cvtpk(float lo, float hi){
    unsigned r;
    asm("v_cvt_pk_bf16_f32 %0, %1, %2" : "=v"(r) : "v"(lo), "v"(hi));
    return r;
}
__device__ inline float r_diag(int j) {
    return (j < 16 || j == 39) ? 100000.0f : 0.001f;
}

// ---------------------------------------------------------------------------
// kF_abcr: fused M -> GJ32 -> D22 -> R_cal -> Rinv (proven).
// ---------------------------------------------------------------------------
__global__ __launch_bounds__(1024) void kF_abcr(
    const float* __restrict__ X3, const float* __restrict__ Y3,
    const float* __restrict__ Z3, float* __restrict__ ws)
{
    __shared__ float Msh[32*33];
    __shared__ float A32[32*33];
    __shared__ float D22s[2048];
    __shared__ float RC[64*68];
    __shared__ float piv[2][64];
    __shared__ float fcol[2][64];
    __shared__ float ipd[2];
    const int t = threadIdx.x;
    const int i = t >> 5, j = t & 31;
    {
        float s = 0.f;
        for (int k = 0; k < 32; ++k)
            s += X3[k*32+i]*X3[k*32+j] + Z3[k*32+i]*Z3[k*32+j];
        s += Y3[i*32+j] - Y3[j*32+i];
        if (i == j) s += 0.001f;
        Msh[i*33+j] = s;
        A32[i*33+j] = s + (i == j ? 1.f : 0.f);
    }
    __syncthreads();
    for (int k = 0; k < 32; ++k) {
        float ip = 1.f / A32[k*33+k];
        float f  = A32[i*33+k];
        float pj = A32[k*33+j];
        __syncthreads();
        float nv;
        if (i == k) nv = (j == k) ? ip : pj*ip;
        else        nv = (j == k) ? (-f*ip) : (A32[i*33+j] - f*ip*pj);
        A32[i*33+j] = nv;
        __syncthreads();
    }
    for (int idx = t; idx < 2048; idx += 1024) {
        int i2 = idx >> 6, j2 = idx & 63;
        float s = 0.f;
        if (j2 < 32) {
            for (int k = 0; k < 32; ++k) {
                float im = (k == j2 ? 1.f : 0.f) - Msh[k*33+j2];
                s += A32[i2*33+k]*im;
            }
        } else {
            int jj = j2 - 32;
            for (int k = 0; k < 32; ++k) s += A32[i2*33+k]*Z3[jj*32+k];
            s *= -2.f;
        }
        float d22 = s * sqrtf(r_diag(j2)) * 0.31622776601683794f;
        D22s[idx] = d22;
        ws[WS_D22 + idx] = d22;
    }
    __syncthreads();
    for (int idx = t; idx < 4096; idx += 1024) {
        int i2 = idx >> 6, j2 = idx & 63;
        float s = 0.f;
        for (int k = 0; k < 32; ++k) s += D22s[k*64+i2]*D22s[k*64+j2];
        float v = -10.f*s;
        if (i2 == j2) v += r_diag(i2);
        RC[i2*68 + j2] = v;
    }
    __syncthreads();
    {
        const bool act = t < 256;
        const int q = (t >> 6) & 3;
        const int i6 = t & 63;
        const int c0 = q*16;
        float Ar[16] = {};
        if (act) {
            #pragma unroll
            for (int jj = 0; jj < 4; ++jj) {
                float4 v = *(const float4*)(&RC[i6*68 + c0 + jj*4]);
                Ar[jj*4+0]=v.x; Ar[jj*4+1]=v.y; Ar[jj*4+2]=v.z; Ar[jj*4+3]=v.w;
            }
        }
        __syncthreads();
        for (int k = 0; k < 64; ++k) {
            const int b  = k & 1;
            const int kq = k >> 4;
            const int kj = k & 15;
            float f_own = Ar[0];
            #pragma unroll
            for (int jj = 1; jj < 16; ++jj) f_own = (jj == kj) ? Ar[jj] : f_own;
            if (act && q == kq) fcol[b][i6] = f_own;
            if (act && i6 == k) {
                #pragma unroll
                for (int jj = 0; jj < 4; ++jj) {
                    float4 v;
                    v.x = Ar[jj*4+0] + ((q==kq && jj*4+0==kj) ? 1.f : 0.f);
                    v.y = Ar[jj*4+1] + ((q==kq && jj*4+1==kj) ? 1.f : 0.f);
                    v.z = Ar[jj*4+2] + ((q==kq && jj*4+2==kj) ? 1.f : 0.f);
                    v.w = Ar[jj*4+3] + ((q==kq && jj*4+3==kj) ? 1.f : 0.f);
                    *(float4*)(&piv[b][c0 + jj*4]) = v;
                }
                if (q == kq) ipd[b] = 1.f / f_own;
            }
            __syncthreads();
            if (act) {
                const float ipv = ipd[b];
                if (i6 == k) {
                    #pragma unroll
                    for (int jj = 0; jj < 16; ++jj)
                        Ar[jj] = (q==kq && jj==kj) ? ipv : Ar[jj]*ipv;
                } else {
                    const float g = fcol[b][i6] * ipv;
                    #pragma unroll
                    for (int jj = 0; jj < 4; ++jj) {
                        float4 pv = *(const float4*)(&piv[b][c0 + jj*4]);
                        Ar[jj*4+0] -= g*pv.x;
                        Ar[jj*4+1] -= g*pv.y;
                        Ar[jj*4+2] -= g*pv.z;
                        Ar[jj*4+3] -= g*pv.w;
                    }
                }
            }
        }
        if (act) {
            float* Rout = ws + WS_RC + i6*64 + c0;
            #pragma unroll
            for (int jj = 0; jj < 4; ++jj) {
                float4 v;
                v.x=Ar[jj*4+0]; v.y=Ar[jj*4+1]; v.z=Ar[jj*4+2]; v.w=Ar[jj*4+3];
                *(float4*)(Rout + jj*4) = v;
            }
        }
    }
}

// ---------------------------------------------------------------------------
// k_vecrT: fused vec_r + T (proven). 80 blocks x 256.
// ---------------------------------------------------------------------------
__global__ __launch_bounds__(256) void k_vecrT(
    const float* __restrict__ B2, const float* __restrict__ C2,
    const float* __restrict__ D21, const float* __restrict__ D12,
    float* __restrict__ ws)
{
    __shared__ float vrsh[4*64];
    const int t = threadIdx.x;
    const int r = t >> 6, k = t & 63;
    const int i = blockIdx.x*4 + r;
    const float* D22 = ws + WS_D22;
    float v;
    if (i < 128) {
        float s = 0.f;
        for (int kk = 0; kk < 32; ++kk) s += C2[kk*128+i]*D22[kk*64+k];
        v = -10.f*s;
    } else if (i < 192) {
        int ii = i - 128;
        float s = 0.f;
        for (int kk = 0; kk < 32; ++kk) s += D21[kk*64+ii]*D22[kk*64+k];
        v = -10.f*s - D12[ii*64+k];
    } else {
        v = B2[(i-192)*64 + k];
    }
    vrsh[r*64 + k] = v;
    ws[WS_VR + i*64 + k] = v;
    __syncthreads();
    const float* RC = ws + WS_RC;
    float s = 0.f;
    for (int kk = 0; kk < 64; ++kk) s += vrsh[r*64 + kk] * RC[kk*64 + k];
    ws[WS_T + i*64 + k] = s;
}

// ---------------------------------------------------------------------------
// K2: H — symmetric (proven): compute i<=j, mirror-write.
// ---------------------------------------------------------------------------
__global__ void k_H(const float* __restrict__ X, const float* __restrict__ C2,
                    const float* __restrict__ D21, float* __restrict__ ws)
{
    int idx = blockIdx.x*256 + threadIdx.x;
    if (idx >= NTOT*NTOT) return;
    int i = idx / NTOT, j = idx % NTOT;
    if (i > j) return;
    float s = (i == j) ? 0.001f : 0.f;
    for (int k = 0; k < NTOT; ++k) s += X[k*NTOT+i]*X[k*NTOT+j];
    const float* T  = ws + WS_T;
    const float* vr = ws + WS_VR;
    float s2 = 0.f;
    for (int k = 0; k < 64; ++k) s2 += T[i*64+k]*vr[j*64+k];
    s += s2;
    if (i < 192 && j < 192) {
        float s3 = 0.f;
        for (int k = 0; k < 32; ++k) {
            float qi = (i < 128) ? C2[k*128+i] : D21[k*64 + (i-128)];
            float qj = (j < 128) ? C2[k*128+j] : D21[k*64 + (j-128)];
            s3 += qi*qj;
        }
        s += 10.f*s3;
    }
    ws[WS_H + i*NTOT + j] = s;
    ws[WS_H + j*NTOT + i] = s;
}

// ---------------------------------------------------------------------------
// K3: extract — now also emits D11T (bf16, transposed, iL on diagonal).
// ---------------------------------------------------------------------------
__global__ void k_extract(const float* __restrict__ Y1, const float* __restrict__ C2,
                          const float* __restrict__ D21, const float* __restrict__ D12,
                          const float* __restrict__ B2, float* __restrict__ ws)
{
    const float* H = ws + WS_H;
    unsigned short* bfb = (unsigned short*)(ws + WS_BFU);
    int tid = blockIdx.x*blockDim.x + threadIdx.x;
    int nth = gridDim.x*blockDim.x;
    for (int idx = tid; idx < 128*128; idx += nth) {
        int i = idx >> 7, j = idx & 127;
        ws[WS_E+idx] = 0.5f*(H[i*320+j] + H[(192+i)*320 + 192+j] + Y1[i*128+j] - Y1[j*128+i]);
    }
    for (int i = tid; i < 64; i += nth)
        ws[WS_ILAM+i] = 2.0f / H[(128+i)*320 + 128+i];
    for (int idx = tid; idx < 64*64; idx += nth) {
        int i = idx >> 6, j = idx & 63;
        float d = (j < i) ? -H[(128+i)*320 + 128+j] : 0.f;
        ws[WS_D11+idx] = d;
        // D11T[j][i] = D11[i][j], diagonal = iL[j]
        float tv = (i == j) ? (2.0f / H[(128+j)*320 + 128+j]) : d;
        bfb[U_D11T + j*64 + i] = f2bf(tv);
    }
    for (int idx = tid; idx < 128*256; idx += nth) {
        int m = idx >> 8, k = idx & 255;
        ws[WS_WEXT+idx] = (k < 192) ? H[(192+m)*320 + k] : B2[m*64 + (k-192)];
    }
    for (int idx = tid; idx < 64*256; idx += nth) {
        int j = idx >> 8, k = idx & 255;
        float v;
        if (k < 128)      v = -H[(128+j)*320 + k];
        else if (k < 192) v = 0.f;
        else              v = D12[j*64 + (k-192)];
        unsigned short hi = f2bf(v);
        bfb[U_WATH+idx] = hi;
        bfb[U_WATL+idx] = f2bf(v - bf2f(hi));
    }
    const float* D22 = ws + WS_D22;
    for (int idx = tid; idx < 32*256; idx += nth) {
        int c = idx >> 8, k = idx & 255;
        float v;
        if (k < 128)      v = C2[c*128+k];
        else if (k < 192) v = D21[c*64 + (k-128)];
        else              v = D22[c*64 + (k-192)];
        bfb[U_WOT+idx] = f2bf(v);
    }
}

// ---------------------------------------------------------------------------
// kS_mega v3 (R25-proven): ILP-4, stride-68 LDS.
// ---------------------------------------------------------------------------
#define LS 68
__global__ __launch_bounds__(256) void kS_mega(float* __restrict__ ws)
{
    __shared__ float AI[64*LS];
    __shared__ float P [64*LS];
    __shared__ float S [64*LS];
    __shared__ float Q [64*LS];
    __shared__ float R2[64*LS];
    __shared__ float Bsh[64*LS];
    __shared__ float Csh[64*LS];
    __shared__ float piv[2][64];
    __shared__ float fcol[2][64];
    __shared__ float ipd[2];
    const int t = threadIdx.x;
    const int q = t >> 6, i6 = t & 63, c0 = q*16;
    const int r0 = t >> 4;
    const int j0 = (t & 15)*4;
    const float* E = ws + WS_E;
    float* EI = ws + WS_EINV;

    for (int idx = t; idx < 4096; idx += 256) {
        int r = idx >> 6, c = idx & 63;
        Bsh[r*LS + c] = E[r*128 + 64 + c];
        Csh[r*LS + c] = E[(64+r)*128 + c];
    }

    {
        float Ar[16];
        {
            const float* Rin = E + i6*128 + c0;
            #pragma unroll
            for (int jj = 0; jj < 4; ++jj) {
                float4 v = *(const float4*)(Rin + jj*4);
                Ar[jj*4+0]=v.x; Ar[jj*4+1]=v.y; Ar[jj*4+2]=v.z; Ar[jj*4+3]=v.w;
            }
        }
        for (int k = 0; k < 64; ++k) {
            const int b  = k & 1;
            const int kq = k >> 4;
            const int kj = k & 15;
            float f_own = Ar[0];
            #pragma unroll
            for (int jj = 1; jj < 16; ++jj) f_own = (jj == kj) ? Ar[jj] : f_own;
            if (q == kq) fcol[b][i6] = f_own;
            if (i6 == k) {
                #pragma unroll
                for (int jj = 0; jj < 4; ++jj) {
                    float4 v;
                    v.x = Ar[jj*4+0] + ((q==kq && jj*4+0==kj) ? 1.f : 0.f);
                    v.y = Ar[jj*4+1] + ((q==kq && jj*4+1==kj) ? 1.f : 0.f);
                    v.z = Ar[jj*4+2] + ((q==kq && jj*4+2==kj) ? 1.f : 0.f);
                    v.w = Ar[jj*4+3] + ((q==kq && jj*4+3==kj) ? 1.f : 0.f);
                    *(float4*)(&piv[b][c0 + jj*4]) = v;
                }
                if (q == kq) ipd[b] = 1.f / f_own;
            }
            __syncthreads();
            const float ipv = ipd[b];
            if (i6 == k) {
                #pragma unroll
                for (int jj = 0; jj < 16; ++jj)
                    Ar[jj] = (q==kq && jj==kj) ? ipv : Ar[jj]*ipv;
            } else {
                const float g = fcol[b][i6] * ipv;
                #pragma unroll
                for (int jj = 0; jj < 4; ++jj) {
                    float4 pv = *(const float4*)(&piv[b][c0 + jj*4]);
                    Ar[jj*4+0] -= g*pv.x;
                    Ar[jj*4+1] -= g*pv.y;
                    Ar[jj*4+2] -= g*pv.z;
                    Ar[jj*4+3] -= g*pv.w;
                }
            }
        }
        #pragma unroll
        for (int jj = 0; jj < 4; ++jj)
            *(float4*)(&AI[i6*LS + c0 + jj*4]) = make_float4(Ar[jj*4+0],Ar[jj*4+1],Ar[jj*4+2],Ar[jj*4+3]);
    }
    __syncthreads();

    {
        float4 a0=make_float4(0,0,0,0), a1=a0, a2=a0, a3=a0;
        #pragma unroll 2
        for (int k = 0; k < 64; ++k) {
            float4 b = *(const float4*)(&Bsh[k*LS + j0]);
            float l0 = AI[(r0    )*LS + k];
            float l1 = AI[(r0+16)*LS + k];
            float l2 = AI[(r0+32)*LS + k];
            float l3 = AI[(r0+48)*LS + k];
            a0.x += l0*b.x; a0.y += l0*b.y; a0.z += l0*b.z; a0.w += l0*b.w;
            a1.x += l1*b.x; a1.y += l1*b.y; a1.z += l1*b.z; a1.w += l1*b.w;
            a2.x += l2*b.x; a2.y += l2*b.y; a2.z += l2*b.z; a2.w += l2*b.w;
            a3.x += l3*b.x; a3.y += l3*b.y; a3.z += l3*b.z; a3.w += l3*b.w;
        }
        *(float4*)(&P[(r0    )*LS + j0]) = a0;
        *(float4*)(&P[(r0+16)*LS + j0]) = a1;
        *(float4*)(&P[(r0+32)*LS + j0]) = a2;
        *(float4*)(&P[(r0+48)*LS + j0]) = a3;
    }
    __syncthreads();

    {
        float4 a0 = *(const float4*)(&E[(64+r0    )*128 + 64 + j0]);
        float4 a1 = *(const float4*)(&E[(64+r0+16)*128 + 64 + j0]);
        float4 a2 = *(const float4*)(&E[(64+r0+32)*128 + 64 + j0]);
        float4 a3 = *(const float4*)(&E[(64+r0+48)*128 + 64 + j0]);
        #pragma unroll 2
        for (int k = 0; k < 64; ++k) {
            float4 b = *(const float4*)(&P[k*LS + j0]);
            float l0 = Csh[(r0    )*LS + k];
            float l1 = Csh[(r0+16)*LS + k];
            float l2 = Csh[(r0+32)*LS + k];
            float l3 = Csh[(r0+48)*LS + k];
            a0.x -= l0*b.x; a0.y -= l0*b.y; a0.z -= l0*b.z; a0.w -= l0*b.w;
            a1.x -= l1*b.x; a1.y -= l1*b.y; a1.z -= l1*b.z; a1.w -= l1*b.w;
            a2.x -= l2*b.x; a2.y -= l2*b.y; a2.z -= l2*b.z; a2.w -= l2*b.w;
            a3.x -= l3*b.x; a3.y -= l3*b.y; a3.z -= l3*b.z; a3.w -= l3*b.w;
        }
        *(float4*)(&S[(r0    )*LS + j0]) = a0;
        *(float4*)(&S[(r0+16)*LS + j0]) = a1;
        *(float4*)(&S[(r0+32)*LS + j0]) = a2;
        *(float4*)(&S[(r0+48)*LS + j0]) = a3;
    }
    __syncthreads();

    {
        float Ar[16];
        #pragma unroll
        for (int jj = 0; jj < 4; ++jj) {
            float4 v = *(const float4*)(&S[i6*LS + c0 + jj*4]);
            Ar[jj*4+0]=v.x; Ar[jj*4+1]=v.y; Ar[jj*4+2]=v.z; Ar[jj*4+3]=v.w;
        }
        __syncthreads();
        for (int k = 0; k < 64; ++k) {
            const int b  = k & 1;
            const int kq = k >> 4;
            const int kj = k & 15;
            float f_own = Ar[0];
            #pragma unroll
            for (int jj = 1; jj < 16; ++jj) f_own = (jj == kj) ? Ar[jj] : f_own;
            if (q == kq) fcol[b][i6] = f_own;
            if (i6 == k) {
                #pragma unroll
                for (int jj = 0; jj < 4; ++jj) {
                    float4 v;
                    v.x = Ar[jj*4+0] + ((q==kq && jj*4+0==kj) ? 1.f : 0.f);
                    v.y = Ar[jj*4+1] + ((q==kq && jj*4+1==kj) ? 1.f : 0.f);
                    v.z = Ar[jj*4+2] + ((q==kq && jj*4+2==kj) ? 1.f : 0.f);
                    v.w = Ar[jj*4+3] + ((q==kq && jj*4+3==kj) ? 1.f : 0.f);
                    *(float4*)(&piv[b][c0 + jj*4]) = v;
                }
                if (q == kq) ipd[b] = 1.f / f_own;
            }
            __syncthreads();
            const float ipv = ipd[b];
            if (i6 == k) {
                #pragma unroll
                for (int jj = 0; jj < 16; ++jj)
                    Ar[jj] = (q==kq && jj==kj) ? ipv : Ar[jj]*ipv;
            } else {
                const float g = fcol[b][i6] * ipv;
                #pragma unroll
                for (int jj = 0; jj < 4; ++jj) {
                    float4 pv = *(const float4*)(&piv[b][c0 + jj*4]);
                    Ar[jj*4+0] -= g*pv.x;
                    Ar[jj*4+1] -= g*pv.y;
                    Ar[jj*4+2] -= g*pv.z;
                    Ar[jj*4+3] -= g*pv.w;
                }
            }
        }
        #pragma unroll
        for (int jj = 0; jj < 4; ++jj)
            *(float4*)(&S[i6*LS + c0 + jj*4]) = make_float4(Ar[jj*4+0],Ar[jj*4+1],Ar[jj*4+2],Ar[jj*4+3]);
    }
    __syncthreads();

    {
        float4 a0=make_float4(0,0,0,0), a1=a0, a2=a0, a3=a0;
        #pragma unroll 2
        for (int k = 0; k < 64; ++k) {
            float4 b = *(const float4*)(&AI[k*LS + j0]);
            float l0 = Csh[(r0    )*LS + k];
            float l1 = Csh[(r0+16)*LS + k];
            float l2 = Csh[(r0+32)*LS + k];
            float l3 = Csh[(r0+48)*LS + k];
            a0.x += l0*b.x; a0.y += l0*b.y; a0.z += l0*b.z; a0.w += l0*b.w;
            a1.x += l1*b.x; a1.y += l1*b.y; a1.z += l1*b.z; a1.w += l1*b.w;
            a2.x += l2*b.x; a2.y += l2*b.y; a2.z += l2*b.z; a2.w += l2*b.w;
            a3.x += l3*b.x; a3.y += l3*b.y; a3.z += l3*b.z; a3.w += l3*b.w;
        }
        *(float4*)(&Q[(r0    )*LS + j0]) = a0;
        *(float4*)(&Q[(r0+16)*LS + j0]) = a1;
        *(float4*)(&Q[(r0+32)*LS + j0]) = a2;
        *(float4*)(&Q[(r0+48)*LS + j0]) = a3;
    }
    __syncthreads();

    {
        float4 a0=make_float4(0,0,0,0), a1=a0, a2=a0, a3=a0;
        #pragma unroll 2
        for (int k = 0; k < 64; ++k) {
            float4 b = *(const float4*)(&Q[k*LS + j0]);
            float l0 = S[(r0    )*LS + k];
            float l1 = S[(r0+16)*LS + k];
            float l2 = S[(r0+32)*LS + k];
            float l3 = S[(r0+48)*LS + k];
            a0.x += l0*b.x; a0.y += l0*b.y; a0.z += l0*b.z; a0.w += l0*b.w;
            a1.x += l1*b.x; a1.y += l1*b.y; a1.z += l1*b.z; a1.w += l1*b.w;
            a2.x += l2*b.x; a2.y += l2*b.y; a2.z += l2*b.z; a2.w += l2*b.w;
            a3.x += l3*b.x; a3.y += l3*b.y; a3.z += l3*b.z; a3.w += l3*b.w;
        }
        *(float4*)(&R2[(r0    )*LS + j0]) = a0;
        *(float4*)(&R2[(r0+16)*LS + j0]) = a1;
        *(float4*)(&R2[(r0+32)*LS + j0]) = a2;
        *(float4*)(&R2[(r0+48)*LS + j0]) = a3;
        *(float4*)(&EI[(64+r0    )*128 + j0]) = make_float4(-a0.x,-a0.y,-a0.z,-a0.w);
        *(float4*)(&EI[(64+r0+16)*128 + j0]) = make_float4(-a1.x,-a1.y,-a1.z,-a1.w);
        *(float4*)(&EI[(64+r0+32)*128 + j0]) = make_float4(-a2.x,-a2.y,-a2.z,-a2.w);
        *(float4*)(&EI[(64+r0+48)*128 + j0]) = make_float4(-a3.x,-a3.y,-a3.z,-a3.w);
    }
    __syncthreads();

    {
        float4 a0 = *(const float4*)(&AI[(r0    )*LS + j0]);
        float4 a1 = *(const float4*)(&AI[(r0+16)*LS + j0]);
        float4 a2 = *(const float4*)(&AI[(r0+32)*LS + j0]);
        float4 a3 = *(const float4*)(&AI[(r0+48)*LS + j0]);
        float4 b0=make_float4(0,0,0,0), b1=b0, b2=b0, b3=b0;
        #pragma unroll 2
        for (int k = 0; k < 64; ++k) {
            float4 br = *(const float4*)(&R2[k*LS + j0]);
            float4 bs = *(const float4*)(&S[k*LS + j0]);
            float l0 = P[(r0    )*LS + k];
            float l1 = P[(r0+16)*LS + k];
            float l2 = P[(r0+32)*LS + k];
            float l3 = P[(r0+48)*LS + k];
            a0.x += l0*br.x; a0.y += l0*br.y; a0.z += l0*br.z; a0.w += l0*br.w;
            a1.x += l1*br.x; a1.y += l1*br.y; a1.z += l1*br.z; a1.w += l1*br.w;
            a2.x += l2*br.x; a2.y += l2*br.y; a2.z += l2*br.z; a2.w += l2*br.w;
            a3.x += l3*br.x; a3.y += l3*br.y; a3.z += l3*br.z; a3.w += l3*br.w;
            b0.x += l0*bs.x; b0.y += l0*bs.y; b0.z += l0*bs.z; b0.w += l0*bs.w;
            b1.x += l1*bs.x; b1.y += l1*bs.y; b1.z += l1*bs.z; b1.w += l1*bs.w;
            b2.x += l2*bs.x; b2.y += l2*bs.y; b2.z += l2*bs.z; b2.w += l2*bs.w;
            b3.x += l3*bs.x; b3.y += l3*bs.y; b3.z += l3*bs.z; b3.w += l3*bs.w;
        }
        *(float4*)(&EI[(r0    )*128 + j0]) = a0;
        *(float4*)(&EI[(r0+16)*128 + j0]) = a1;
        *(float4*)(&EI[(r0+32)*128 + j0]) = a2;
        *(float4*)(&EI[(r0+48)*128 + j0]) = a3;
        *(float4*)(&EI[(r0    )*128 + 64 + j0]) = make_float4(-b0.x,-b0.y,-b0.z,-b0.w);
        *(float4*)(&EI[(r0+16)*128 + 64 + j0]) = make_float4(-b1.x,-b1.y,-b1.z,-b1.w);
        *(float4*)(&EI[(r0+32)*128 + 64 + j0]) = make_float4(-b2.x,-b2.y,-b2.z,-b2.w);
        *(float4*)(&EI[(r0+48)*128 + 64 + j0]) = make_float4(-b3.x,-b3.y,-b3.z,-b3.w);
        *(float4*)(&EI[(64+r0    )*128 + 64 + j0]) = *(const float4*)(&S[(r0    )*LS + j0]);
        *(float4*)(&EI[(64+r0+16)*128 + 64 + j0]) = *(const float4*)(&S[(r0+16)*LS + j0]);
        *(float4*)(&EI[(64+r0+32)*128 + 64 + j0]) = *(const float4*)(&S[(r0+32)*LS + j0]);
        *(float4*)(&EI[(64+r0+48)*128 + 64 + j0]) = *(const float4*)(&S[(r0+48)*LS + j0]);
    }
}

// ---------------------------------------------------------------------------
// K5: Wsp
// ---------------------------------------------------------------------------
__global__ __launch_bounds__(256) void k_Wsp(float* __restrict__ ws)
{
    int i = blockIdx.x;
    int k = threadIdx.x;
    const float* Einv = ws + WS_EINV + i*128;
    const float* WexT = ws + WS_WEXT;
    unsigned short* bfb = (unsigned short*)(ws + WS_BFU);
    float s = 0.f;
    for (int m = 0; m < 128; ++m) s += Einv[m] * WexT[m*256 + k];
    unsigned short hi = f2bf(s);
    bfb[U_WSPH + i*256 + k] = hi;
    bfb[U_WSPL + i*256 + k] = f2bf(s - bf2f(hi));
}

// ---------------------------------------------------------------------------
// K6: batch kernel. LDS = zsh ONLY (32768 B exactly -> 5 blocks/CU target;
// R26 evidence: LDS 40960 gave only 3 blocks, Occ 37.5%).
//  - D11t rows read from GLOBAL (L2-hot, prefetchable, not in wj chain)
//  - iL via per-lane register + __shfl (no load in the serial chain)
// ---------------------------------------------------------------------------
__global__ __launch_bounds__(256, 5) void k_batch(
    const float* __restrict__ inpt, const float* __restrict__ state,
    const float* __restrict__ ws, float* __restrict__ out)
{
    __shared__ unsigned short zsh[64*256];    // 32768 B exactly
    const int t = threadIdx.x;
    const int row0 = blockIdx.x * 64;
    const unsigned short* bfb = (const unsigned short*)(ws + WS_BFU);
    const unsigned short* D11Tg = bfb + U_D11T;

    for (int idx = t; idx < 64*16; idx += 256) {
        int r = idx >> 4, c = idx & 15;
        const float4* p = (const float4*)(state + (size_t)(row0+r)*128 + c*8);
        float4 f0 = p[0], f1 = p[1];
        uint4 hv;
        hv.x = cvtpk(f0.x, f0.y);
        hv.y = cvtpk(f0.z, f0.w);
        hv.z = cvtpk(f1.x, f1.y);
        hv.w = cvtpk(f1.z, f1.w);
        *(uint4*)(&zsh[r*256 + ((c ^ (r&7)) << 3)]) = hv;
    }
    for (int idx = t; idx < 64*8; idx += 256) {
        int r = idx >> 3, cl = idx & 7, c = 24 + cl;
        const float4* p = (const float4*)(inpt + (size_t)(row0+r)*64 + cl*8);
        float4 f0 = p[0], f1 = p[1];
        uint4 hv;
        hv.x = cvtpk(f0.x, f0.y);
        hv.y = cvtpk(f0.z, f0.w);
        hv.z = cvtpk(f1.x, f1.y);
        hv.w = cvtpk(f1.z, f1.w);
        *(uint4*)(&zsh[r*256 + ((c ^ (r&7)) << 3)]) = hv;
    }
    __syncthreads();

    const int wv = t >> 6, lane = t & 63, lr = lane & 15, lk = lane >> 4;

    {
        const unsigned short* WATH = bfb + U_WATH;
        const unsigned short* WATL = bfb + U_WATL;
        f32x4 acc1[4] = {};
        const int ks1[6] = {0,1,2,3,6,7};
        #pragma unroll
        for (int s = 0; s < 6; ++s) {
            int ks = ks1[s];
            short8 bh = *(const short8*)(&WATH[(wv*16+lr)*256 + ks*32 + lk*8]);
            short8 bl = *(const short8*)(&WATL[(wv*16+lr)*256 + ks*32 + lk*8]);
            #pragma unroll
            for (int rt = 0; rt < 4; ++rt) {
                int row = rt*16 + lr, c = ks*4 + lk;
                short8 a = *(const short8*)(&zsh[row*256 + ((c ^ (row&7)) << 3)]);
                acc1[rt] = __builtin_amdgcn_mfma_f32_16x16x32_bf16(a, bh, acc1[rt], 0, 0, 0);
                acc1[rt] = __builtin_amdgcn_mfma_f32_16x16x32_bf16(a, bl, acc1[rt], 0, 0, 0);
            }
        }
        __syncthreads();
        const int ac = wv*16 + lr;
        const int cch = 16 + (ac >> 3), coff = ac & 7;
        #pragma unroll
        for (int rt = 0; rt < 4; ++rt)
            #pragma unroll
            for (int r = 0; r < 4; ++r) {
                int row = rt*16 + lk*4 + r;
                zsh[row*256 + ((cch ^ (row&7)) << 3) + coff] = f2bf(acc1[rt][r]);
            }
    }
    __syncthreads();

    {
        const int r  = wv*16 + (lane >> 2);
        const int qq = lane & 3;
        // iL via register + shfl (lane l holds iL[l]; diag of D11T)
        float iLreg = bf2f(D11Tg[lane*64 + lane]);
        float acc[16];
        {
            short8 a0v = *(const short8*)(&zsh[r*256 + (((16+qq*2  ) ^ (r&7)) << 3)]);
            short8 a1v = *(const short8*)(&zsh[r*256 + (((16+qq*2+1) ^ (r&7)) << 3)]);
            #pragma unroll
            for (int s = 0; s < 8; ++s) {
                acc[s]   = bf2f((unsigned short)a0v[s]);
                acc[8+s] = bf2f((unsigned short)a1v[s]);
            }
        }
        float wloc[16];
        #pragma unroll
        for (int j = 0; j < 64; ++j) {
            float diag = __shfl(iLreg, j, 64);
            float v = acc[j & 15];
            float x = v * diag;
            float e = __expf(2.f*x);
            float wc = 1.f - __fdividef(2.f, e + 1.f);
            int src = (lane & 0x3C) | (j >> 4);
            float wj = __shfl(wc, src, 64);
            if ((j >> 4) == qq) wloc[j & 15] = wj;
            // D11T row slice from GLOBAL (32B, L2-hot, not in wj chain)
            short8 d0 = *(const short8*)(&D11Tg[j*64 + qq*16]);
            short8 d1 = *(const short8*)(&D11Tg[j*64 + qq*16 + 8]);
            #pragma unroll
            for (int s = 0; s < 8; ++s) {
                acc[s]   += wj * bf2f((unsigned short)d0[s]);
                acc[8+s] += wj * bf2f((unsigned short)d1[s]);
            }
        }
        {
            uint4 h0, h1;
            h0.x = cvtpk(wloc[0],  wloc[1]);  h0.y = cvtpk(wloc[2],  wloc[3]);
            h0.z = cvtpk(wloc[4],  wloc[5]);  h0.w = cvtpk(wloc[6],  wloc[7]);
            h1.x = cvtpk(wloc[8],  wloc[9]);  h1.y = cvtpk(wloc[10], wloc[11]);
            h1.z = cvtpk(wloc[12], wloc[13]); h1.w = cvtpk(wloc[14], wloc[15]);
            *(uint4*)(&zsh[r*256 + (((16+qq*2  ) ^ (r&7)) << 3)]) = h0;
            *(uint4*)(&zsh[r*256 + (((16+qq*2+1) ^ (r&7)) << 3)]) = h1;
        }
    }
    __syncthreads();

    {
        const unsigned short* WOT  = bfb + U_WOT;
        const unsigned short* WSPH = bfb + U_WSPH;
        const unsigned short* WSPL = bfb + U_WSPL;
        f32x4 acc[3][4] = {};
        const int nt = (wv < 2) ? 3 : 2;
        #pragma unroll
        for (int ks = 0; ks < 8; ++ks) {
            short8 afr[4];
            #pragma unroll
            for (int rt = 0; rt < 4; ++rt) {
                int row = rt*16 + lr, c = ks*4 + lk;
                afr[rt] = *(const short8*)(&zsh[row*256 + ((c ^ (row&7)) << 3)]);
            }
            #pragma unroll
            for (int tt = 0; tt < 3; ++tt) {
                if (tt < nt) {
                    int ct = wv + tt*4;
                    if (ct < 2) {
                        short8 b = *(const short8*)(&WOT[(ct*16+lr)*256 + ks*32 + lk*8]);
                        #pragma unroll
                        for (int rt = 0; rt < 4; ++rt)
                            acc[tt][rt] = __builtin_amdgcn_mfma_f32_16x16x32_bf16(afr[rt], b, acc[tt][rt], 0, 0, 0);
                    } else {
                        short8 bh = *(const short8*)(&WSPH[((ct-2)*16+lr)*256 + ks*32 + lk*8]);
                        short8 bl = *(const short8*)(&WSPL[((ct-2)*16+lr)*256 + ks*32 + lk*8]);
                        #pragma unroll
                        for (int rt = 0; rt < 4; ++rt) {
                            acc[tt][rt] = __builtin_amdgcn_mfma_f32_16x16x32_bf16(afr[rt], bh, acc[tt][rt], 0, 0, 0);
                            acc[tt][rt] = __builtin_amdgcn_mfma_f32_16x16x32_bf16(afr[rt], bl, acc[tt][rt], 0, 0, 0);
                        }
                    }
                }
            }
        }
        float* sp = out + (size_t)BATCH*32;
        #pragma unroll
        for (int tt = 0; tt < 3; ++tt) {
            if (tt < nt) {
                int ct = wv + tt*4;
                #pragma unroll
                for (int rt = 0; rt < 4; ++rt) {
                    int rowb = row0 + rt*16 + lk*4;
                    #pragma unroll
                    for (int r = 0; r < 4; ++r) {
                        float vv = acc[tt][rt][r];
                        if (ct < 2) out[(size_t)(rowb+r)*32  + ct*16 + lr]     = vv;
                        else        sp[(size_t)(rowb+r)*128 + (ct-2)*16 + lr] = vv;
                    }
                }
            }
        }
    }
}

extern "C" void kernel_launch(void* const* d_in, const int* in_sizes, int n_in,
                              void* d_out, int out_size, void* d_ws, size_t ws_size,
                              hipStream_t stream)
{
    const float* inpt  = (const float*)d_in[0];
    const float* state = (const float*)d_in[1];
    const float* X   = (const float*)d_in[2];
    const float* Y1  = (const float*)d_in[3];
    const float* X3  = (const float*)d_in[4];
    const float* Y3  = (const float*)d_in[5];
    const float* Z3  = (const float*)d_in[6];
    const float* B2  = (const float*)d_in[7];
    const float* C2  = (const float*)d_in[8];
    const float* D21 = (const float*)d_in[9];
    const float* D12 = (const float*)d_in[10];
    float* ws  = (float*)d_ws;
    float* out = (float*)d_out;

    kF_abcr<<<1, 1024, 0, stream>>>(X3, Y3, Z3, ws);
    k_vecrT<<<80, 256, 0, stream>>>(B2, C2, D21, D12, ws);
    k_H<<<(NTOT*NTOT + 255)/256, 256, 0, stream>>>(X, C2, D21, ws);
    k_extract<<<128, 256, 0, stream>>>(Y1, C2, D21, D12, B2, ws);
    kS_mega<<<1, 256, 0, stream>>>(ws);
    k_Wsp<<<128, 256, 0, stream>>>(ws);
    k_batch<<<BATCH/64, 256, 0, stream>>>(inpt, state, ws, out);
}

// Round 28
// 278.193 us; speedup vs baseline: 1.0159x; 1.0159x over previous
//
#include <hip/hip_runtime.h>
#include <math.h>

#define BATCH 131072
#define NTOT 320

typedef __attribute__((ext_vector_type(8))) short short8;
typedef __attribute__((ext_vector_type(4))) float f32x4;

// ---- ws layout (float offsets) ----
#define WS_D22   0          // 32*64
#define WS_VR    2048       // 320*64
#define WS_T     22528      // 320*64
#define WS_H     43008      // 320*320
#define WS_E     145408     // 128*128
#define WS_EINV  161792     // 128*128
#define WS_WEXT  178176     // 128*256
#define WS_D11   210944     // 64*64
#define WS_ILAM  215040     // 64
#define WS_BFU   215104     // ushort region below
#define U_WATH 0
#define U_WATL 16384
#define U_WOT  32768
#define U_WSPH 40960
#define U_WSPL 73728
// transient scratch inside WS_H:
#define WS_RC   (WS_H + 2048)   // 64*64  Rinv

__device__ inline unsigned short f2bf(float x){
    unsigned u = __builtin_bit_cast(unsigned, x);
    u += 0x7FFFu + ((u >> 16) & 1u);
    return (unsigned short)(u >> 16);
}
__device__ inline float bf2f(unsigned short h){
    unsigned u = ((unsigned)h) << 16;
    return __builtin_bit_cast(float, u);
}
// v_cvt_pk_bf16_f32: packs bf16(lo) into [15:0], bf16(hi) into [31:16]. RNE,
// bit-identical to f2bf. No builtin on gfx950 -> inline asm (guide T12).
__device__ inline unsigned cvtpk(float lo, float hi){
    unsigned r;
    asm("v_cvt_pk_bf16_f32 %0, %1, %2" : "=v"(r) : "v"(lo), "v"(hi));
    return r;
}
__device__ inline float r_diag(int j) {
    return (j < 16 || j == 39) ? 100000.0f : 0.001f;
}

// ---------------------------------------------------------------------------
// kF_abcr: fused M -> GJ32 -> D22 -> R_cal -> Rinv (proven).
// ---------------------------------------------------------------------------
__global__ __launch_bounds__(1024) void kF_abcr(
    const float* __restrict__ X3, const float* __restrict__ Y3,
    const float* __restrict__ Z3, float* __restrict__ ws)
{
    __shared__ float Msh[32*33];
    __shared__ float A32[32*33];
    __shared__ float D22s[2048];
    __shared__ float RC[64*68];
    __shared__ float piv[2][64];
    __shared__ float fcol[2][64];
    __shared__ float ipd[2];
    const int t = threadIdx.x;
    const int i = t >> 5, j = t & 31;
    {
        float s = 0.f;
        for (int k = 0; k < 32; ++k)
            s += X3[k*32+i]*X3[k*32+j] + Z3[k*32+i]*Z3[k*32+j];
        s += Y3[i*32+j] - Y3[j*32+i];
        if (i == j) s += 0.001f;
        Msh[i*33+j] = s;
        A32[i*33+j] = s + (i == j ? 1.f : 0.f);
    }
    __syncthreads();
    for (int k = 0; k < 32; ++k) {
        float ip = 1.f / A32[k*33+k];
        float f  = A32[i*33+k];
        float pj = A32[k*33+j];
        __syncthreads();
        float nv;
        if (i == k) nv = (j == k) ? ip : pj*ip;
        else        nv = (j == k) ? (-f*ip) : (A32[i*33+j] - f*ip*pj);
        A32[i*33+j] = nv;
        __syncthreads();
    }
    for (int idx = t; idx < 2048; idx += 1024) {
        int i2 = idx >> 6, j2 = idx & 63;
        float s = 0.f;
        if (j2 < 32) {
            for (int k = 0; k < 32; ++k) {
                float im = (k == j2 ? 1.f : 0.f) - Msh[k*33+j2];
                s += A32[i2*33+k]*im;
            }
        } else {
            int jj = j2 - 32;
            for (int k = 0; k < 32; ++k) s += A32[i2*33+k]*Z3[jj*32+k];
            s *= -2.f;
        }
        float d22 = s * sqrtf(r_diag(j2)) * 0.31622776601683794f;
        D22s[idx] = d22;
        ws[WS_D22 + idx] = d22;
    }
    __syncthreads();
    for (int idx = t; idx < 4096; idx += 1024) {
        int i2 = idx >> 6, j2 = idx & 63;
        float s = 0.f;
        for (int k = 0; k < 32; ++k) s += D22s[k*64+i2]*D22s[k*64+j2];
        float v = -10.f*s;
        if (i2 == j2) v += r_diag(i2);
        RC[i2*68 + j2] = v;
    }
    __syncthreads();
    {
        const bool act = t < 256;
        const int q = (t >> 6) & 3;
        const int i6 = t & 63;
        const int c0 = q*16;
        float Ar[16] = {};
        if (act) {
            #pragma unroll
            for (int jj = 0; jj < 4; ++jj) {
                float4 v = *(const float4*)(&RC[i6*68 + c0 + jj*4]);
                Ar[jj*4+0]=v.x; Ar[jj*4+1]=v.y; Ar[jj*4+2]=v.z; Ar[jj*4+3]=v.w;
            }
        }
        __syncthreads();
        for (int k = 0; k < 64; ++k) {
            const int b  = k & 1;
            const int kq = k >> 4;
            const int kj = k & 15;
            float f_own = Ar[0];
            #pragma unroll
            for (int jj = 1; jj < 16; ++jj) f_own = (jj == kj) ? Ar[jj] : f_own;
            if (act && q == kq) fcol[b][i6] = f_own;
            if (act && i6 == k) {
                #pragma unroll
                for (int jj = 0; jj < 4; ++jj) {
                    float4 v;
                    v.x = Ar[jj*4+0] + ((q==kq && jj*4+0==kj) ? 1.f : 0.f);
                    v.y = Ar[jj*4+1] + ((q==kq && jj*4+1==kj) ? 1.f : 0.f);
                    v.z = Ar[jj*4+2] + ((q==kq && jj*4+2==kj) ? 1.f : 0.f);
                    v.w = Ar[jj*4+3] + ((q==kq && jj*4+3==kj) ? 1.f : 0.f);
                    *(float4*)(&piv[b][c0 + jj*4]) = v;
                }
                if (q == kq) ipd[b] = 1.f / f_own;
            }
            __syncthreads();
            if (act) {
                const float ipv = ipd[b];
                if (i6 == k) {
                    #pragma unroll
                    for (int jj = 0; jj < 16; ++jj)
                        Ar[jj] = (q==kq && jj==kj) ? ipv : Ar[jj]*ipv;
                } else {
                    const float g = fcol[b][i6] * ipv;
                    #pragma unroll
                    for (int jj = 0; jj < 4; ++jj) {
                        float4 pv = *(const float4*)(&piv[b][c0 + jj*4]);
                        Ar[jj*4+0] -= g*pv.x;
                        Ar[jj*4+1] -= g*pv.y;
                        Ar[jj*4+2] -= g*pv.z;
                        Ar[jj*4+3] -= g*pv.w;
                    }
                }
            }
        }
        if (act) {
            float* Rout = ws + WS_RC + i6*64 + c0;
            #pragma unroll
            for (int jj = 0; jj < 4; ++jj) {
                float4 v;
                v.x=Ar[jj*4+0]; v.y=Ar[jj*4+1]; v.z=Ar[jj*4+2]; v.w=Ar[jj*4+3];
                *(float4*)(Rout + jj*4) = v;
            }
        }
    }
}

// ---------------------------------------------------------------------------
// k_vecrT: fused vec_r + T (proven). 80 blocks x 256.
// ---------------------------------------------------------------------------
__global__ __launch_bounds__(256) void k_vecrT(
    const float* __restrict__ B2, const float* __restrict__ C2,
    const float* __restrict__ D21, const float* __restrict__ D12,
    float* __restrict__ ws)
{
    __shared__ float vrsh[4*64];
    const int t = threadIdx.x;
    const int r = t >> 6, k = t & 63;
    const int i = blockIdx.x*4 + r;
    const float* D22 = ws + WS_D22;
    float v;
    if (i < 128) {
        float s = 0.f;
        for (int kk = 0; kk < 32; ++kk) s += C2[kk*128+i]*D22[kk*64+k];
        v = -10.f*s;
    } else if (i < 192) {
        int ii = i - 128;
        float s = 0.f;
        for (int kk = 0; kk < 32; ++kk) s += D21[kk*64+ii]*D22[kk*64+k];
        v = -10.f*s - D12[ii*64+k];
    } else {
        v = B2[(i-192)*64 + k];
    }
    vrsh[r*64 + k] = v;
    ws[WS_VR + i*64 + k] = v;
    __syncthreads();
    const float* RC = ws + WS_RC;
    float s = 0.f;
    for (int kk = 0; kk < 64; ++kk) s += vrsh[r*64 + kk] * RC[kk*64 + k];
    ws[WS_T + i*64 + k] = s;
}

// ---------------------------------------------------------------------------
// K2: H — symmetric (proven): compute i<=j, mirror-write.
// ---------------------------------------------------------------------------
__global__ void k_H(const float* __restrict__ X, const float* __restrict__ C2,
                    const float* __restrict__ D21, float* __restrict__ ws)
{
    int idx = blockIdx.x*256 + threadIdx.x;
    if (idx >= NTOT*NTOT) return;
    int i = idx / NTOT, j = idx % NTOT;
    if (i > j) return;
    float s = (i == j) ? 0.001f : 0.f;
    for (int k = 0; k < NTOT; ++k) s += X[k*NTOT+i]*X[k*NTOT+j];
    const float* T  = ws + WS_T;
    const float* vr = ws + WS_VR;
    float s2 = 0.f;
    for (int k = 0; k < 64; ++k) s2 += T[i*64+k]*vr[j*64+k];
    s += s2;
    if (i < 192 && j < 192) {
        float s3 = 0.f;
        for (int k = 0; k < 32; ++k) {
            float qi = (i < 128) ? C2[k*128+i] : D21[k*64 + (i-128)];
            float qj = (j < 128) ? C2[k*128+j] : D21[k*64 + (j-128)];
            s3 += qi*qj;
        }
        s += 10.f*s3;
    }
    ws[WS_H + i*NTOT + j] = s;
    ws[WS_H + j*NTOT + i] = s;
}

// ---------------------------------------------------------------------------
// K3: extract
// ---------------------------------------------------------------------------
__global__ void k_extract(const float* __restrict__ Y1, const float* __restrict__ C2,
                          const float* __restrict__ D21, const float* __restrict__ D12,
                          const float* __restrict__ B2, float* __restrict__ ws)
{
    const float* H = ws + WS_H;
    unsigned short* bfb = (unsigned short*)(ws + WS_BFU);
    int tid = blockIdx.x*blockDim.x + threadIdx.x;
    int nth = gridDim.x*blockDim.x;
    for (int idx = tid; idx < 128*128; idx += nth) {
        int i = idx >> 7, j = idx & 127;
        ws[WS_E+idx] = 0.5f*(H[i*320+j] + H[(192+i)*320 + 192+j] + Y1[i*128+j] - Y1[j*128+i]);
    }
    for (int i = tid; i < 64; i += nth)
        ws[WS_ILAM+i] = 2.0f / H[(128+i)*320 + 128+i];
    for (int idx = tid; idx < 64*64; idx += nth) {
        int i = idx >> 6, j = idx & 63;
        ws[WS_D11+idx] = (j < i) ? -H[(128+i)*320 + 128+j] : 0.f;
    }
    for (int idx = tid; idx < 128*256; idx += nth) {
        int m = idx >> 8, k = idx & 255;
        ws[WS_WEXT+idx] = (k < 192) ? H[(192+m)*320 + k] : B2[m*64 + (k-192)];
    }
    for (int idx = tid; idx < 64*256; idx += nth) {
        int j = idx >> 8, k = idx & 255;
        float v;
        if (k < 128)      v = -H[(128+j)*320 + k];
        else if (k < 192) v = 0.f;
        else              v = D12[j*64 + (k-192)];
        unsigned short hi = f2bf(v);
        bfb[U_WATH+idx] = hi;
        bfb[U_WATL+idx] = f2bf(v - bf2f(hi));
    }
    const float* D22 = ws + WS_D22;
    for (int idx = tid; idx < 32*256; idx += nth) {
        int c = idx >> 8, k = idx & 255;
        float v;
        if (k < 128)      v = C2[c*128+k];
        else if (k < 192) v = D21[c*64 + (k-128)];
        else              v = D22[c*64 + (k-192)];
        bfb[U_WOT+idx] = f2bf(v);
    }
}

// ---------------------------------------------------------------------------
// kS_mega v3 (R25-proven): ILP-4, stride-68 LDS.
// ---------------------------------------------------------------------------
#define LS 68
__global__ __launch_bounds__(256) void kS_mega(float* __restrict__ ws)
{
    __shared__ float AI[64*LS];
    __shared__ float P [64*LS];
    __shared__ float S [64*LS];
    __shared__ float Q [64*LS];
    __shared__ float R2[64*LS];
    __shared__ float Bsh[64*LS];
    __shared__ float Csh[64*LS];
    __shared__ float piv[2][64];
    __shared__ float fcol[2][64];
    __shared__ float ipd[2];
    const int t = threadIdx.x;
    const int q = t >> 6, i6 = t & 63, c0 = q*16;
    const int r0 = t >> 4;
    const int j0 = (t & 15)*4;
    const float* E = ws + WS_E;
    float* EI = ws + WS_EINV;

    for (int idx = t; idx < 4096; idx += 256) {
        int r = idx >> 6, c = idx & 63;
        Bsh[r*LS + c] = E[r*128 + 64 + c];
        Csh[r*LS + c] = E[(64+r)*128 + c];
    }

    {
        float Ar[16];
        {
            const float* Rin = E + i6*128 + c0;
            #pragma unroll
            for (int jj = 0; jj < 4; ++jj) {
                float4 v = *(const float4*)(Rin + jj*4);
                Ar[jj*4+0]=v.x; Ar[jj*4+1]=v.y; Ar[jj*4+2]=v.z; Ar[jj*4+3]=v.w;
            }
        }
        for (int k = 0; k < 64; ++k) {
            const int b  = k & 1;
            const int kq = k >> 4;
            const int kj = k & 15;
            float f_own = Ar[0];
            #pragma unroll
            for (int jj = 1; jj < 16; ++jj) f_own = (jj == kj) ? Ar[jj] : f_own;
            if (q == kq) fcol[b][i6] = f_own;
            if (i6 == k) {
                #pragma unroll
                for (int jj = 0; jj < 4; ++jj) {
                    float4 v;
                    v.x = Ar[jj*4+0] + ((q==kq && jj*4+0==kj) ? 1.f : 0.f);
                    v.y = Ar[jj*4+1] + ((q==kq && jj*4+1==kj) ? 1.f : 0.f);
                    v.z = Ar[jj*4+2] + ((q==kq && jj*4+2==kj) ? 1.f : 0.f);
                    v.w = Ar[jj*4+3] + ((q==kq && jj*4+3==kj) ? 1.f : 0.f);
                    *(float4*)(&piv[b][c0 + jj*4]) = v;
                }
                if (q == kq) ipd[b] = 1.f / f_own;
            }
            __syncthreads();
            const float ipv = ipd[b];
            if (i6 == k) {
                #pragma unroll
                for (int jj = 0; jj < 16; ++jj)
                    Ar[jj] = (q==kq && jj==kj) ? ipv : Ar[jj]*ipv;
            } else {
                const float g = fcol[b][i6] * ipv;
                #pragma unroll
                for (int jj = 0; jj < 4; ++jj) {
                    float4 pv = *(const float4*)(&piv[b][c0 + jj*4]);
                    Ar[jj*4+0] -= g*pv.x;
                    Ar[jj*4+1] -= g*pv.y;
                    Ar[jj*4+2] -= g*pv.z;
                    Ar[jj*4+3] -= g*pv.w;
                }
            }
        }
        #pragma unroll
        for (int jj = 0; jj < 4; ++jj)
            *(float4*)(&AI[i6*LS + c0 + jj*4]) = make_float4(Ar[jj*4+0],Ar[jj*4+1],Ar[jj*4+2],Ar[jj*4+3]);
    }
    __syncthreads();

    {
        float4 a0=make_float4(0,0,0,0), a1=a0, a2=a0, a3=a0;
        #pragma unroll 2
        for (int k = 0; k < 64; ++k) {
            float4 b = *(const float4*)(&Bsh[k*LS + j0]);
            float l0 = AI[(r0    )*LS + k];
            float l1 = AI[(r0+16)*LS + k];
            float l2 = AI[(r0+32)*LS + k];
            float l3 = AI[(r0+48)*LS + k];
            a0.x += l0*b.x; a0.y += l0*b.y; a0.z += l0*b.z; a0.w += l0*b.w;
            a1.x += l1*b.x; a1.y += l1*b.y; a1.z += l1*b.z; a1.w += l1*b.w;
            a2.x += l2*b.x; a2.y += l2*b.y; a2.z += l2*b.z; a2.w += l2*b.w;
            a3.x += l3*b.x; a3.y += l3*b.y; a3.z += l3*b.z; a3.w += l3*b.w;
        }
        *(float4*)(&P[(r0    )*LS + j0]) = a0;
        *(float4*)(&P[(r0+16)*LS + j0]) = a1;
        *(float4*)(&P[(r0+32)*LS + j0]) = a2;
        *(float4*)(&P[(r0+48)*LS + j0]) = a3;
    }
    __syncthreads();

    {
        float4 a0 = *(const float4*)(&E[(64+r0    )*128 + 64 + j0]);
        float4 a1 = *(const float4*)(&E[(64+r0+16)*128 + 64 + j0]);
        float4 a2 = *(const float4*)(&E[(64+r0+32)*128 + 64 + j0]);
        float4 a3 = *(const float4*)(&E[(64+r0+48)*128 + 64 + j0]);
        #pragma unroll 2
        for (int k = 0; k < 64; ++k) {
            float4 b = *(const float4*)(&P[k*LS + j0]);
            float l0 = Csh[(r0    )*LS + k];
            float l1 = Csh[(r0+16)*LS + k];
            float l2 = Csh[(r0+32)*LS + k];
            float l3 = Csh[(r0+48)*LS + k];
            a0.x -= l0*b.x; a0.y -= l0*b.y; a0.z -= l0*b.z; a0.w -= l0*b.w;
            a1.x -= l1*b.x; a1.y -= l1*b.y; a1.z -= l1*b.z; a1.w -= l1*b.w;
            a2.x -= l2*b.x; a2.y -= l2*b.y; a2.z -= l2*b.z; a2.w -= l2*b.w;
            a3.x -= l3*b.x; a3.y -= l3*b.y; a3.z -= l3*b.z; a3.w -= l3*b.w;
        }
        *(float4*)(&S[(r0    )*LS + j0]) = a0;
        *(float4*)(&S[(r0+16)*LS + j0]) = a1;
        *(float4*)(&S[(r0+32)*LS + j0]) = a2;
        *(float4*)(&S[(r0+48)*LS + j0]) = a3;
    }
    __syncthreads();

    {
        float Ar[16];
        #pragma unroll
        for (int jj = 0; jj < 4; ++jj) {
            float4 v = *(const float4*)(&S[i6*LS + c0 + jj*4]);
            Ar[jj*4+0]=v.x; Ar[jj*4+1]=v.y; Ar[jj*4+2]=v.z; Ar[jj*4+3]=v.w;
        }
        __syncthreads();
        for (int k = 0; k < 64; ++k) {
            const int b  = k & 1;
            const int kq = k >> 4;
            const int kj = k & 15;
            float f_own = Ar[0];
            #pragma unroll
            for (int jj = 1; jj < 16; ++jj) f_own = (jj == kj) ? Ar[jj] : f_own;
            if (q == kq) fcol[b][i6] = f_own;
            if (i6 == k) {
                #pragma unroll
                for (int jj = 0; jj < 4; ++jj) {
                    float4 v;
                    v.x = Ar[jj*4+0] + ((q==kq && jj*4+0==kj) ? 1.f : 0.f);
                    v.y = Ar[jj*4+1] + ((q==kq && jj*4+1==kj) ? 1.f : 0.f);
                    v.z = Ar[jj*4+2] + ((q==kq && jj*4+2==kj) ? 1.f : 0.f);
                    v.w = Ar[jj*4+3] + ((q==kq && jj*4+3==kj) ? 1.f : 0.f);
                    *(float4*)(&piv[b][c0 + jj*4]) = v;
                }
                if (q == kq) ipd[b] = 1.f / f_own;
            }
            __syncthreads();
            const float ipv = ipd[b];
            if (i6 == k) {
                #pragma unroll
                for (int jj = 0; jj < 16; ++jj)
                    Ar[jj] = (q==kq && jj==kj) ? ipv : Ar[jj]*ipv;
            } else {
                const float g = fcol[b][i6] * ipv;
                #pragma unroll
                for (int jj = 0; jj < 4; ++jj) {
                    float4 pv = *(const float4*)(&piv[b][c0 + jj*4]);
                    Ar[jj*4+0] -= g*pv.x;
                    Ar[jj*4+1] -= g*pv.y;
                    Ar[jj*4+2] -= g*pv.z;
                    Ar[jj*4+3] -= g*pv.w;
                }
            }
        }
        #pragma unroll
        for (int jj = 0; jj < 4; ++jj)
            *(float4*)(&S[i6*LS + c0 + jj*4]) = make_float4(Ar[jj*4+0],Ar[jj*4+1],Ar[jj*4+2],Ar[jj*4+3]);
    }
    __syncthreads();

    {
        float4 a0=make_float4(0,0,0,0), a1=a0, a2=a0, a3=a0;
        #pragma unroll 2
        for (int k = 0; k < 64; ++k) {
            float4 b = *(const float4*)(&AI[k*LS + j0]);
            float l0 = Csh[(r0    )*LS + k];
            float l1 = Csh[(r0+16)*LS + k];
            float l2 = Csh[(r0+32)*LS + k];
            float l3 = Csh[(r0+48)*LS + k];
            a0.x += l0*b.x; a0.y += l0*b.y; a0.z += l0*b.z; a0.w += l0*b.w;
            a1.x += l1*b.x; a1.y += l1*b.y; a1.z += l1*b.z; a1.w += l1*b.w;
            a2.x += l2*b.x; a2.y += l2*b.y; a2.z += l2*b.z; a2.w += l2*b.w;
            a3.x += l3*b.x; a3.y += l3*b.y; a3.z += l3*b.z; a3.w += l3*b.w;
        }
        *(float4*)(&Q[(r0    )*LS + j0]) = a0;
        *(float4*)(&Q[(r0+16)*LS + j0]) = a1;
        *(float4*)(&Q[(r0+32)*LS + j0]) = a2;
        *(float4*)(&Q[(r0+48)*LS + j0]) = a3;
    }
    __syncthreads();

    {
        float4 a0=make_float4(0,0,0,0), a1=a0, a2=a0, a3=a0;
        #pragma unroll 2
        for (int k = 0; k < 64; ++k) {
            float4 b = *(const float4*)(&Q[k*LS + j0]);
            float l0 = S[(r0    )*LS + k];
            float l1 = S[(r0+16)*LS + k];
            float l2 = S[(r0+32)*LS + k];
            float l3 = S[(r0+48)*LS + k];
            a0.x += l0*b.x; a0.y += l0*b.y; a0.z += l0*b.z; a0.w += l0*b.w;
            a1.x += l1*b.x; a1.y += l1*b.y; a1.z += l1*b.z; a1.w += l1*b.w;
            a2.x += l2*b.x; a2.y += l2*b.y; a2.z += l2*b.z; a2.w += l2*b.w;
            a3.x += l3*b.x; a3.y += l3*b.y; a3.z += l3*b.z; a3.w += l3*b.w;
        }
        *(float4*)(&R2[(r0    )*LS + j0]) = a0;
        *(float4*)(&R2[(r0+16)*LS + j0]) = a1;
        *(float4*)(&R2[(r0+32)*LS + j0]) = a2;
        *(float4*)(&R2[(r0+48)*LS + j0]) = a3;
        *(float4*)(&EI[(64+r0    )*128 + j0]) = make_float4(-a0.x,-a0.y,-a0.z,-a0.w);
        *(float4*)(&EI[(64+r0+16)*128 + j0]) = make_float4(-a1.x,-a1.y,-a1.z,-a1.w);
        *(float4*)(&EI[(64+r0+32)*128 + j0]) = make_float4(-a2.x,-a2.y,-a2.z,-a2.w);
        *(float4*)(&EI[(64+r0+48)*128 + j0]) = make_float4(-a3.x,-a3.y,-a3.z,-a3.w);
    }
    __syncthreads();

    {
        float4 a0 = *(const float4*)(&AI[(r0    )*LS + j0]);
        float4 a1 = *(const float4*)(&AI[(r0+16)*LS + j0]);
        float4 a2 = *(const float4*)(&AI[(r0+32)*LS + j0]);
        float4 a3 = *(const float4*)(&AI[(r0+48)*LS + j0]);
        float4 b0=make_float4(0,0,0,0), b1=b0, b2=b0, b3=b0;
        #pragma unroll 2
        for (int k = 0; k < 64; ++k) {
            float4 br = *(const float4*)(&R2[k*LS + j0]);
            float4 bs = *(const float4*)(&S[k*LS + j0]);
            float l0 = P[(r0    )*LS + k];
            float l1 = P[(r0+16)*LS + k];
            float l2 = P[(r0+32)*LS + k];
            float l3 = P[(r0+48)*LS + k];
            a0.x += l0*br.x; a0.y += l0*br.y; a0.z += l0*br.z; a0.w += l0*br.w;
            a1.x += l1*br.x; a1.y += l1*br.y; a1.z += l1*br.z; a1.w += l1*br.w;
            a2.x += l2*br.x; a2.y += l2*br.y; a2.z += l2*br.z; a2.w += l2*br.w;
            a3.x += l3*br.x; a3.y += l3*br.y; a3.z += l3*br.z; a3.w += l3*br.w;
            b0.x += l0*bs.x; b0.y += l0*bs.y; b0.z += l0*bs.z; b0.w += l0*bs.w;
            b1.x += l1*bs.x; b1.y += l1*bs.y; b1.z += l1*bs.z; b1.w += l1*bs.w;
            b2.x += l2*bs.x; b2.y += l2*bs.y; b2.z += l2*bs.z; b2.w += l2*bs.w;
            b3.x += l3*bs.x; b3.y += l3*bs.y; b3.z += l3*bs.z; b3.w += l3*bs.w;
        }
        *(float4*)(&EI[(r0    )*128 + j0]) = a0;
        *(float4*)(&EI[(r0+16)*128 + j0]) = a1;
        *(float4*)(&EI[(r0+32)*128 + j0]) = a2;
        *(float4*)(&EI[(r0+48)*128 + j0]) = a3;
        *(float4*)(&EI[(r0    )*128 + 64 + j0]) = make_float4(-b0.x,-b0.y,-b0.z,-b0.w);
        *(float4*)(&EI[(r0+16)*128 + 64 + j0]) = make_float4(-b1.x,-b1.y,-b1.z,-b1.w);
        *(float4*)(&EI[(r0+32)*128 + 64 + j0]) = make_float4(-b2.x,-b2.y,-b2.z,-b2.w);
        *(float4*)(&EI[(r0+48)*128 + 64 + j0]) = make_float4(-b3.x,-b3.y,-b3.z,-b3.w);
        *(float4*)(&EI[(64+r0    )*128 + 64 + j0]) = *(const float4*)(&S[(r0    )*LS + j0]);
        *(float4*)(&EI[(64+r0+16)*128 + 64 + j0]) = *(const float4*)(&S[(r0+16)*LS + j0]);
        *(float4*)(&EI[(64+r0+32)*128 + 64 + j0]) = *(const float4*)(&S[(r0+32)*LS + j0]);
        *(float4*)(&EI[(64+r0+48)*128 + 64 + j0]) = *(const float4*)(&S[(r0+48)*LS + j0]);
    }
}

// ---------------------------------------------------------------------------
// K5: Wsp
// ---------------------------------------------------------------------------
__global__ __launch_bounds__(256) void k_Wsp(float* __restrict__ ws)
{
    int i = blockIdx.x;
    int k = threadIdx.x;
    const float* Einv = ws + WS_EINV + i*128;
    const float* WexT = ws + WS_WEXT;
    unsigned short* bfb = (unsigned short*)(ws + WS_BFU);
    float s = 0.f;
    for (int m = 0; m < 128; ++m) s += Einv[m] * WexT[m*256 + k];
    unsigned short hi = f2bf(s);
    bfb[U_WSPH + i*256 + k] = hi;
    bfb[U_WSPL + i*256 + k] = f2bf(s - bf2f(hi));
}

// ---------------------------------------------------------------------------
// K6: batch kernel — R26-EXACT (best measured: ~114us, total 278.9us).
// LDS D11t + cvt_pk staging + vectorized recurrence reads.
// ---------------------------------------------------------------------------
__global__ __launch_bounds__(256, 4) void k_batch(
    const float* __restrict__ inpt, const float* __restrict__ state,
    const float* __restrict__ ws, float* __restrict__ out)
{
    __shared__ unsigned short zsh[64*256];    // 32768 B
    __shared__ unsigned short D11t[64*64];    // 8192 B (transposed, bf16)
    const int t = threadIdx.x;
    const int row0 = blockIdx.x * 64;
    const unsigned short* bfb = (const unsigned short*)(ws + WS_BFU);

    for (int idx = t; idx < 64*16; idx += 256) {
        int r = idx >> 4, c = idx & 15;
        const float4* p = (const float4*)(state + (size_t)(row0+r)*128 + c*8);
        float4 f0 = p[0], f1 = p[1];
        uint4 hv;
        hv.x = cvtpk(f0.x, f0.y);
        hv.y = cvtpk(f0.z, f0.w);
        hv.z = cvtpk(f1.x, f1.y);
        hv.w = cvtpk(f1.z, f1.w);
        *(uint4*)(&zsh[r*256 + ((c ^ (r&7)) << 3)]) = hv;
    }
    for (int idx = t; idx < 64*8; idx += 256) {
        int r = idx >> 3, cl = idx & 7, c = 24 + cl;
        const float4* p = (const float4*)(inpt + (size_t)(row0+r)*64 + cl*8);
        float4 f0 = p[0], f1 = p[1];
        uint4 hv;
        hv.x = cvtpk(f0.x, f0.y);
        hv.y = cvtpk(f0.z, f0.w);
        hv.z = cvtpk(f1.x, f1.y);
        hv.w = cvtpk(f1.z, f1.w);
        *(uint4*)(&zsh[r*256 + ((c ^ (r&7)) << 3)]) = hv;
    }
    for (int idx = t; idx < 4096; idx += 256) {
        int j = idx >> 6, i = idx & 63;
        float v = (i == j) ? ws[WS_ILAM + j] : ws[WS_D11 + i*64 + j];
        D11t[idx] = f2bf(v);
    }
    __syncthreads();

    const int wv = t >> 6, lane = t & 63, lr = lane & 15, lk = lane >> 4;

    {
        const unsigned short* WATH = bfb + U_WATH;
        const unsigned short* WATL = bfb + U_WATL;
        f32x4 acc1[4] = {};
        const int ks1[6] = {0,1,2,3,6,7};
        #pragma unroll
        for (int s = 0; s < 6; ++s) {
            int ks = ks1[s];
            short8 bh = *(const short8*)(&WATH[(wv*16+lr)*256 + ks*32 + lk*8]);
            short8 bl = *(const short8*)(&WATL[(wv*16+lr)*256 + ks*32 + lk*8]);
            #pragma unroll
            for (int rt = 0; rt < 4; ++rt) {
                int row = rt*16 + lr, c = ks*4 + lk;
                short8 a = *(const short8*)(&zsh[row*256 + ((c ^ (row&7)) << 3)]);
                acc1[rt] = __builtin_amdgcn_mfma_f32_16x16x32_bf16(a, bh, acc1[rt], 0, 0, 0);
                acc1[rt] = __builtin_amdgcn_mfma_f32_16x16x32_bf16(a, bl, acc1[rt], 0, 0, 0);
            }
        }
        __syncthreads();
        const int ac = wv*16 + lr;
        const int cch = 16 + (ac >> 3), coff = ac & 7;
        #pragma unroll
        for (int rt = 0; rt < 4; ++rt)
            #pragma unroll
            for (int r = 0; r < 4; ++r) {
                int row = rt*16 + lk*4 + r;
                zsh[row*256 + ((cch ^ (row&7)) << 3) + coff] = f2bf(acc1[rt][r]);
            }
    }
    __syncthreads();

    {
        const int r  = wv*16 + (lane >> 2);
        const int qq = lane & 3;
        float acc[16];
        {
            short8 a0v = *(const short8*)(&zsh[r*256 + (((16+qq*2  ) ^ (r&7)) << 3)]);
            short8 a1v = *(const short8*)(&zsh[r*256 + (((16+qq*2+1) ^ (r&7)) << 3)]);
            #pragma unroll
            for (int s = 0; s < 8; ++s) {
                acc[s]   = bf2f((unsigned short)a0v[s]);
                acc[8+s] = bf2f((unsigned short)a1v[s]);
            }
        }
        float wloc[16];
        #pragma unroll
        for (int j = 0; j < 64; ++j) {
            float diag = bf2f(D11t[j*64 + j]);
            float v = acc[j & 15];
            float x = v * diag;
            float e = __expf(2.f*x);
            float wc = 1.f - __fdividef(2.f, e + 1.f);
            int src = (lane & 0x3C) | (j >> 4);
            float wj = __shfl(wc, src, 64);
            if ((j >> 4) == qq) wloc[j & 15] = wj;
            short8 d0 = *(const short8*)(&D11t[j*64 + qq*16]);
            short8 d1 = *(const short8*)(&D11t[j*64 + qq*16 + 8]);
            #pragma unroll
            for (int s = 0; s < 8; ++s) {
                acc[s]   += wj * bf2f((unsigned short)d0[s]);
                acc[8+s] += wj * bf2f((unsigned short)d1[s]);
            }
        }
        {
            uint4 h0, h1;
            h0.x = cvtpk(wloc[0],  wloc[1]);  h0.y = cvtpk(wloc[2],  wloc[3]);
            h0.z = cvtpk(wloc[4],  wloc[5]);  h0.w = cvtpk(wloc[6],  wloc[7]);
            h1.x = cvtpk(wloc[8],  wloc[9]);  h1.y = cvtpk(wloc[10], wloc[11]);
            h1.z = cvtpk(wloc[12], wloc[13]); h1.w = cvtpk(wloc[14], wloc[15]);
            *(uint4*)(&zsh[r*256 + (((16+qq*2  ) ^ (r&7)) << 3)]) = h0;
            *(uint4*)(&zsh[r*256 + (((16+qq*2+1) ^ (r&7)) << 3)]) = h1;
        }
    }
    __syncthreads();

    {
        const unsigned short* WOT  = bfb + U_WOT;
        const unsigned short* WSPH = bfb + U_WSPH;
        const unsigned short* WSPL = bfb + U_WSPL;
        f32x4 acc[3][4] = {};
        const int nt = (wv < 2) ? 3 : 2;
        #pragma unroll
        for (int ks = 0; ks < 8; ++ks) {
            short8 afr[4];
            #pragma unroll
            for (int rt = 0; rt < 4; ++rt) {
                int row = rt*16 + lr, c = ks*4 + lk;
                afr[rt] = *(const short8*)(&zsh[row*256 + ((c ^ (row&7)) << 3)]);
            }
            #pragma unroll
            for (int tt = 0; tt < 3; ++tt) {
                if (tt < nt) {
                    int ct = wv + tt*4;
                    if (ct < 2) {
                        short8 b = *(const short8*)(&WOT[(ct*16+lr)*256 + ks*32 + lk*8]);
                        #pragma unroll
                        for (int rt = 0; rt < 4; ++rt)
                            acc[tt][rt] = __builtin_amdgcn_mfma_f32_16x16x32_bf16(afr[rt], b, acc[tt][rt], 0, 0, 0);
                    } else {
                        short8 bh = *(const short8*)(&WSPH[((ct-2)*16+lr)*256 + ks*32 + lk*8]);
                        short8 bl = *(const short8*)(&WSPL[((ct-2)*16+lr)*256 + ks*32 + lk*8]);
                        #pragma unroll
                        for (int rt = 0; rt < 4; ++rt) {
                            acc[tt][rt] = __builtin_amdgcn_mfma_f32_16x16x32_bf16(afr[rt], bh, acc[tt][rt], 0, 0, 0);
                            acc[tt][rt] = __builtin_amdgcn_mfma_f32_16x16x32_bf16(afr[rt], bl, acc[tt][rt], 0, 0, 0);
                        }
                    }
                }
            }
        }
        float* sp = out + (size_t)BATCH*32;
        #pragma unroll
        for (int tt = 0; tt < 3; ++tt) {
            if (tt < nt) {
                int ct = wv + tt*4;
                #pragma unroll
                for (int rt = 0; rt < 4; ++rt) {
                    int rowb = row0 + rt*16 + lk*4;
                    #pragma unroll
                    for (int r = 0; r < 4; ++r) {
                        float vv = acc[tt][rt][r];
                        if (ct < 2) out[(size_t)(rowb+r)*32  + ct*16 + lr]     = vv;
                        else        sp[(size_t)(rowb+r)*128 + (ct-2)*16 + lr] = vv;
                    }
                }
            }
        }
    }
}

extern "C" void kernel_launch(void* const* d_in, const int* in_sizes, int n_in,
                              void* d_out, int out_size, void* d_ws, size_t ws_size,
                              hipStream_t stream)
{
    const float* inpt  = (const float*)d_in[0];
    const float* state = (const float*)d_in[1];
    const float* X   = (const float*)d_in[2];
    const float* Y1  = (const float*)d_in[3];
    const float* X3  = (const float*)d_in[4];
    const float* Y3  = (const float*)d_in[5];
    const float* Z3  = (const float*)d_in[6];
    const float* B2  = (const float*)d_in[7];
    const float* C2  = (const float*)d_in[8];
    const float* D21 = (const float*)d_in[9];
    const float* D12 = (const float*)d_in[10];
    float* ws  = (float*)d_ws;
    float* out = (float*)d_out;

    kF_abcr<<<1, 1024, 0, stream>>>(X3, Y3, Z3, ws);
    k_vecrT<<<80, 256, 0, stream>>>(B2, C2, D21, D12, ws);
    k_H<<<(NTOT*NTOT + 255)/256, 256, 0, stream>>>(X, C2, D21, ws);
    k_extract<<<128, 256, 0, stream>>>(Y1, C2, D21, D12, B2, ws);
    kS_mega<<<1, 256, 0, stream>>>(ws);
    k_Wsp<<<128, 256, 0, stream>>>(ws);
    k_batch<<<BATCH/64, 256, 0, stream>>>(inpt, state, ws, out);
}